// Round 5
// baseline (82.743 us; speedup 1.0000x reference)
//
#include <hip/hip_runtime.h>
#include <cstdint>

#define PEDS   64
#define HIDDEN 128
#define POOL   64
#define GRIDG  4
#define NBHD   2.0f

typedef unsigned short u16;
typedef unsigned int   u32;
typedef __attribute__((ext_vector_type(8))) short bf16x8;
typedef __attribute__((ext_vector_type(4))) float f32x4;

__device__ __forceinline__ u16 f2bf(float f) {
    u32 u = __float_as_uint(f);
    u += 0x7fffu + ((u >> 16) & 1u);   // RNE
    return (u16)(u >> 16);
}
__device__ __forceinline__ u32 pack2bf(float a, float b) {
    return (u32)f2bf(a) | ((u32)f2bf(b) << 16);
}

// Single kernel: no LDS, no barriers, no prep. Grid = (scene, channel-half),
// block = 4 waves. Wave mt owns output rows i in [mt*16,+16), cols c in
// [ch*32,+32). out = sum_g M_g @ (h @ W_g), both matmuls MFMA, wave-local:
//  - GEMM1 computes hw[all 64 j][32 c] (32 MFMA/cell) with j-rows PERMUTED
//    (jrow = (mtile>>1)*32 + (l15>>2)*8 + (mtile&1)*4 + (l15&3)) so that the
//    C/D fragment layout coincides with GEMM2's B-operand layout per-lane:
//    hw[kk*32+q*8+e][ni*16+l15] == acc1[kk*2+(e>>2)][ni][e&3]. Handoff is
//    pure register packing.
//  - GEMM2 (4 MFMA/cell) uses M-frags built from in-register gidx bytes.
//  - W B-frags load straight from fp32 w (k-consecutive dwords, stride 256B,
//    L1/L2-resident), packed to bf16 in registers; next cell prefetched.
__global__ __launch_bounds__(256, 2) void social_onepass(
    const float* __restrict__ h, const float* __restrict__ pos,
    const float* __restrict__ w, const float* __restrict__ bias,
    float* __restrict__ out)
{
    const int tid  = threadIdx.x;
    const int mt   = tid >> 6;
    const int lane = tid & 63;
    const int l15  = lane & 15;
    const int q    = lane >> 4;
    const int scene = blockIdx.x >> 1;
    const int ch    = blockIdx.x & 1;

    // ---- positions: lane l -> ped l (per wave) ----
    float2 pp = ((const float2*)pos)[(size_t)scene * PEDS + lane];

    // ---- in-register gidx for exactly this lane's GEMM2 A-frag pairs ----
    const int i = mt * 16 + l15;
    const float pxi = __shfl(pp.x, i), pyi = __shfl(pp.y, i);
    const float scale = (float)GRIDG / (2.0f * NBHD);
    u32 gpk[4] = {0u, 0u, 0u, 0u};
    u32 um = 0u;
#pragma unroll
    for (int kk = 0; kk < 2; ++kk) {
#pragma unroll
        for (int e = 0; e < 8; ++e) {
            int j = kk * 32 + q * 8 + e;
            float rx = __shfl(pp.x, j) - pxi;
            float ry = __shfl(pp.y, j) - pyi;
            u32 gb = 0xffu;
            if ((i != j) && (fabsf(rx) <= NBHD) && (fabsf(ry) <= NBHD)) {
                int gx = (int)floorf((rx + NBHD) * scale); gx = min(max(gx, 0), GRIDG - 1);
                int gy = (int)floorf((ry + NBHD) * scale); gy = min(max(gy, 0), GRIDG - 1);
                gb = (u32)(gy * GRIDG + gx);
                um |= 1u << gb;
            }
            gpk[kk * 2 + (e >> 2)] |= gb << ((e & 3) * 8);
        }
    }
#pragma unroll
    for (int off = 32; off; off >>= 1) um |= __shfl_xor(um, off);
    um = __builtin_amdgcn_readfirstlane(um);   // wave-uniform used-cell mask

    // ---- h A-frags (16): permuted rows, k = st4*32 + q*8 + e ----
    const float* hbase = h + (size_t)scene * (PEDS * HIDDEN);
    const int jrow = (l15 >> 2) * 8 + (l15 & 3);
    bf16x8 af[16];
#pragma unroll
    for (int mtile = 0; mtile < 4; ++mtile) {
        int jr = (mtile >> 1) * 32 + (mtile & 1) * 4 + jrow;
        const float* rp = hbase + (size_t)jr * HIDDEN + q * 8;
#pragma unroll
        for (int st4 = 0; st4 < 4; ++st4) {
            float4 f0 = *(const float4*)(rp + st4 * 32);
            float4 f1 = *(const float4*)(rp + st4 * 32 + 4);
            union { u32 u[4]; bf16x8 v; } uu;
            uu.u[0] = pack2bf(f0.x, f0.y);
            uu.u[1] = pack2bf(f0.z, f0.w);
            uu.u[2] = pack2bf(f1.x, f1.y);
            uu.u[3] = pack2bf(f1.z, f1.w);
            af[mtile * 4 + st4] = uu.v;
        }
    }

    const float bv0 = bias[ch * 32 + l15];
    const float bv1 = bias[ch * 32 + 16 + l15];
    f32x4 oacc0 = (f32x4){0.f, 0.f, 0.f, 0.f};
    f32x4 oacc1 = (f32x4){0.f, 0.f, 0.f, 0.f};

    const int ng = __popc(um);
    u32 rem = um;
    int g = 0;
    float wf32[64];
    const float* wb = w + ch * 32 + l15;
    if (ng) {
        g = __ffs(rem) - 1; rem &= rem - 1u;
#pragma unroll
        for (int f = 0; f < 8; ++f) {                 // f = ni*4 + st4
            int ni = f >> 2, st4 = f & 3;
            const float* src = wb + ((size_t)(g * HIDDEN + st4 * 32 + q * 8)) * POOL + ni * 16;
#pragma unroll
            for (int e = 0; e < 8; ++e) wf32[f * 8 + e] = src[(size_t)e * POOL];
        }
    }

    for (int t = 0; t < ng; ++t) {
        // pack current cell's W frags (frees wf32 for prefetch)
        bf16x8 wfrag[8];
#pragma unroll
        for (int f = 0; f < 8; ++f) {
            union { u32 u[4]; bf16x8 v; } uu;
            uu.u[0] = pack2bf(wf32[f * 8 + 0], wf32[f * 8 + 1]);
            uu.u[1] = pack2bf(wf32[f * 8 + 2], wf32[f * 8 + 3]);
            uu.u[2] = pack2bf(wf32[f * 8 + 4], wf32[f * 8 + 5]);
            uu.u[3] = pack2bf(wf32[f * 8 + 6], wf32[f * 8 + 7]);
            wfrag[f] = uu.v;
        }
        const int gcur = g;
        if (rem) {                                   // prefetch next cell's W
            g = __ffs(rem) - 1; rem &= rem - 1u;
#pragma unroll
            for (int f = 0; f < 8; ++f) {
                int ni = f >> 2, st4 = f & 3;
                const float* src = wb + ((size_t)(g * HIDDEN + st4 * 32 + q * 8)) * POOL + ni * 16;
#pragma unroll
                for (int e = 0; e < 8; ++e) wf32[f * 8 + e] = src[(size_t)e * POOL];
            }
        }

        // ---- GEMM1: hw[j, c], all 64 j x this block's 32 c ----
        f32x4 acc1[4][2];
#pragma unroll
        for (int a = 0; a < 4; ++a) {
            acc1[a][0] = (f32x4){0.f, 0.f, 0.f, 0.f};
            acc1[a][1] = (f32x4){0.f, 0.f, 0.f, 0.f};
        }
#pragma unroll
        for (int st4 = 0; st4 < 4; ++st4) {
#pragma unroll
            for (int mtile = 0; mtile < 4; ++mtile) {
                acc1[mtile][0] = __builtin_amdgcn_mfma_f32_16x16x32_bf16(
                    af[mtile * 4 + st4], wfrag[st4], acc1[mtile][0], 0, 0, 0);
                acc1[mtile][1] = __builtin_amdgcn_mfma_f32_16x16x32_bf16(
                    af[mtile * 4 + st4], wfrag[4 + st4], acc1[mtile][1], 0, 0, 0);
            }
        }

        // ---- GEMM2: oacc += M_g @ hw (B-frags are lane-local repacks) ----
#pragma unroll
        for (int kk = 0; kk < 2; ++kk) {
            u32 wa = gpk[kk * 2], wc = gpk[kk * 2 + 1];
            union { u16 hx[8]; bf16x8 v; } mu;
#pragma unroll
            for (int b = 0; b < 4; ++b)
                mu.hx[b]     = (((wa >> (b * 8)) & 0xffu) == (u32)gcur) ? (u16)0x3F80 : (u16)0;
#pragma unroll
            for (int b = 0; b < 4; ++b)
                mu.hx[4 + b] = (((wc >> (b * 8)) & 0xffu) == (u32)gcur) ? (u16)0x3F80 : (u16)0;
#pragma unroll
            for (int ni = 0; ni < 2; ++ni) {
                union { u32 u[4]; bf16x8 v; } bb;
                bb.u[0] = pack2bf(acc1[kk * 2][ni][0],     acc1[kk * 2][ni][1]);
                bb.u[1] = pack2bf(acc1[kk * 2][ni][2],     acc1[kk * 2][ni][3]);
                bb.u[2] = pack2bf(acc1[kk * 2 + 1][ni][0], acc1[kk * 2 + 1][ni][1]);
                bb.u[3] = pack2bf(acc1[kk * 2 + 1][ni][2], acc1[kk * 2 + 1][ni][3]);
                if (ni == 0)
                    oacc0 = __builtin_amdgcn_mfma_f32_16x16x32_bf16(mu.v, bb.v, oacc0, 0, 0, 0);
                else
                    oacc1 = __builtin_amdgcn_mfma_f32_16x16x32_bf16(mu.v, bb.v, oacc1, 0, 0, 0);
            }
        }
    }

    // ---- epilogue: i = mt*16 + q*4 + r, c = ch*32 + ni*16 + l15 ----
    size_t ob = ((size_t)scene * PEDS + mt * 16 + q * 4) * POOL + ch * 32 + l15;
#pragma unroll
    for (int r = 0; r < 4; ++r) {
        out[ob + (size_t)r * POOL]      = oacc0[r] + bv0;
        out[ob + (size_t)r * POOL + 16] = oacc1[r] + bv1;
    }
}

extern "C" void kernel_launch(void* const* d_in, const int* in_sizes, int n_in,
                              void* d_out, int out_size, void* d_ws, size_t ws_size,
                              hipStream_t stream) {
    const float* h    = (const float*)d_in[0];
    const float* pos  = (const float*)d_in[1];
    const float* w    = (const float*)d_in[2];
    const float* bias = (const float*)d_in[3];
    float* out = (float*)d_out;

    const int total = in_sizes[0] / HIDDEN;   // 16384
    const int B     = total / PEDS;           // 256

    hipLaunchKernelGGL(social_onepass, dim3(B * 2), dim3(256), 0, stream,
                       h, pos, w, bias, out);
}

// Round 6
// 72.710 us; speedup vs baseline: 1.1380x; 1.1380x over previous
//
#include <hip/hip_runtime.h>
#include <cstdint>

#define PEDS   64
#define HIDDEN 128
#define POOL   64
#define GRIDG  4
#define NBHD   2.0f

typedef unsigned short u16;
typedef unsigned int   u32;
typedef __attribute__((ext_vector_type(8))) short bf16x8;
typedef __attribute__((ext_vector_type(4))) float f32x4;

__device__ __forceinline__ u16 f2bf(float f) {
    u32 u = __float_as_uint(f);
    u += 0x7fffu + ((u >> 16) & 1u);   // RNE
    return (u16)(u >> 16);
}
__device__ __forceinline__ u32 pack2bf(float a, float b) {
    return (u32)f2bf(a) | ((u32)f2bf(b) << 16);
}

// Single kernel. Grid = (scene, channel-half), block = 256 (4 waves).
// out = sum_g M_g @ (h @ W_g), both matmuls MFMA.
// Wave wv: GEMM1 j-rows [wv*16,+16) x 32 c (j-split, no redundancy);
//          GEMM2 i-rows [wv*16,+16) x 32 c, M-frags from in-register gidx.
// LDS 48KB: wtab (W bf16 frag-native, 4 cells) 32K | hwT (GEMM2-B frag) 16K.
// 3 barriers typical (mask, wtab, hwT). 2-3 blocks/CU for latency overlap.
__global__ __launch_bounds__(256, 3) void social_r6(
    const float* __restrict__ h, const float* __restrict__ pos,
    const float* __restrict__ w, const float* __restrict__ bias,
    float* __restrict__ out)
{
    __shared__ u16 wtab[16384];   // [t][st4][ni][L=q*16+l15][8]  (16B chunks)
    __shared__ u16 hwT[8192];     // [t][kk][c4][ni][l15][8]
    __shared__ u32 wmask[4];

    const int tid  = threadIdx.x;
    const int wv   = tid >> 6;
    const int lane = tid & 63;
    const int l15  = lane & 15;
    const int q    = lane >> 4;
    const int scene = blockIdx.x >> 1;
    const int ch    = blockIdx.x & 1;

    // ---- positions; lane l holds ped l ----
    float2 pp = ((const float2*)pos)[(size_t)scene * PEDS + lane];

    // ---- in-register gidx for this lane's GEMM2 A-frag pairs ----
    // i = wv*16 + l15 (A-operand m=l15), j = kk*32 + q*8 + e (k=q*8+e)
    const int i = wv * 16 + l15;
    const float pxi = __shfl(pp.x, i), pyi = __shfl(pp.y, i);
    const float scale = (float)GRIDG / (2.0f * NBHD);
    u32 gpk[4] = {0u, 0u, 0u, 0u};
    u32 um = 0u;
#pragma unroll
    for (int kk = 0; kk < 2; ++kk) {
#pragma unroll
        for (int e = 0; e < 8; ++e) {
            int j = kk * 32 + q * 8 + e;
            float rx = __shfl(pp.x, j) - pxi;
            float ry = __shfl(pp.y, j) - pyi;
            u32 gb = 0xffu;
            if ((i != j) && (fabsf(rx) <= NBHD) && (fabsf(ry) <= NBHD)) {
                int gx = (int)floorf((rx + NBHD) * scale); gx = min(max(gx, 0), GRIDG - 1);
                int gy = (int)floorf((ry + NBHD) * scale); gy = min(max(gy, 0), GRIDG - 1);
                gb = (u32)(gy * GRIDG + gx);
                um |= 1u << gb;
            }
            gpk[kk * 2 + (e >> 2)] |= gb << ((e & 3) * 8);
        }
    }
#pragma unroll
    for (int off = 32; off; off >>= 1) um |= __shfl_xor(um, off);
    if (lane == 0) wmask[wv] = um;

    // ---- GEMM1 A-frags direct from global: row j = wv*16+l15, k = st4*32+q*8 ----
    bf16x8 af[4];
    {
        const float* hr = h + ((size_t)scene * PEDS + wv * 16 + l15) * HIDDEN + q * 8;
#pragma unroll
        for (int st4 = 0; st4 < 4; ++st4) {
            float4 f0 = *(const float4*)(hr + st4 * 32);
            float4 f1 = *(const float4*)(hr + st4 * 32 + 4);
            union { u32 u[4]; bf16x8 v; } uu;
            uu.u[0] = pack2bf(f0.x, f0.y);
            uu.u[1] = pack2bf(f0.z, f0.w);
            uu.u[2] = pack2bf(f1.x, f1.y);
            uu.u[3] = pack2bf(f1.z, f1.w);
            af[st4] = uu.v;
        }
    }
    const float bv0 = bias[ch * 32 + l15];
    const float bv1 = bias[ch * 32 + 16 + l15];

    __syncthreads();                                  // B0: wmask visible
    u32 mask = wmask[0] | wmask[1] | wmask[2] | wmask[3];
    mask = __builtin_amdgcn_readfirstlane(mask);

    f32x4 oacc0 = (f32x4){0.f, 0.f, 0.f, 0.f};
    f32x4 oacc1 = (f32x4){0.f, 0.f, 0.f, 0.f};

    const int np = __popc(mask);
    const int nb = np ? (np + 3) >> 2 : 1;
    u32 rem = mask;

    // staging role: half-block stages 2 slots; thread = (c4 0..7, koct 0..15)
    const int tl    = tid & 127;
    const int c4    = tl & 7;
    const int koct  = tl >> 3;
    const int slot0 = (tid >> 7) * 2;

    for (int b = 0; b < nb; ++b) {
        int gs[4];
#pragma unroll
        for (int t = 0; t < 4; ++t) {
            gs[t] = rem ? (__ffs(rem) - 1) : -1;
            if (rem) rem &= rem - 1u;
        }
        if (b) __syncthreads();                       // protect wtab/hwT reuse

        // ---- stage W -> wtab (frag-native bf16) ----
#pragma unroll
        for (int tt = 0; tt < 2; ++tt) {
            int t  = slot0 + tt;
            int ge = gs[t] < 0 ? 0 : gs[t];
            const float* src = w + ((size_t)(ge * HIDDEN + koct * 8)) * POOL + ch * 32 + c4 * 4;
            float4 v[8];
#pragma unroll
            for (int e = 0; e < 8; ++e) v[e] = *(const float4*)(src + (size_t)e * POOL);
            const float* vp = (const float*)v;
            int st4 = koct >> 2, ni = c4 >> 2;
            int Lb  = (koct & 3) * 16 + (c4 & 3) * 4;
            uint4* dst = (uint4*)wtab + ((t * 4 + st4) * 2 + ni) * 64 + Lb;
#pragma unroll
            for (int ii = 0; ii < 4; ++ii) {
                dst[ii] = make_uint4(
                    pack2bf(vp[0 * 4 + ii], vp[1 * 4 + ii]),
                    pack2bf(vp[2 * 4 + ii], vp[3 * 4 + ii]),
                    pack2bf(vp[4 * 4 + ii], vp[5 * 4 + ii]),
                    pack2bf(vp[6 * 4 + ii], vp[7 * 4 + ii]));
            }
        }
        __syncthreads();                              // B1: wtab staged

        // ---- GEMM1: hw[j in wave's 16 rows][32 c] for all 4 slots ----
        const int kkw = wv >> 1;
        const int c4w = (wv & 1) * 2 + (q >> 1);
        const int e0  = (q & 1) * 4;
#pragma unroll
        for (int t = 0; t < 4; ++t) {
            f32x4 a10 = (f32x4){0.f, 0.f, 0.f, 0.f};
            f32x4 a11 = (f32x4){0.f, 0.f, 0.f, 0.f};
#pragma unroll
            for (int st4 = 0; st4 < 4; ++st4) {
                bf16x8 b0 = *(const bf16x8*)&wtab[(((t * 4 + st4) * 2 + 0) * 64 + lane) * 8];
                bf16x8 b1 = *(const bf16x8*)&wtab[(((t * 4 + st4) * 2 + 1) * 64 + lane) * 8];
                a10 = __builtin_amdgcn_mfma_f32_16x16x32_bf16(af[st4], b0, a10, 0, 0, 0);
                a11 = __builtin_amdgcn_mfma_f32_16x16x32_bf16(af[st4], b1, a11, 0, 0, 0);
            }
            // lane holds hw[j = wv*16 + q*4 + r][c = ni*16 + l15] in a1x[r]
            *(uint2*)&hwT[((((t * 2 + kkw) * 4 + c4w) * 2 + 0) * 16 + l15) * 8 + e0] =
                make_uint2(pack2bf(a10[0], a10[1]), pack2bf(a10[2], a10[3]));
            *(uint2*)&hwT[((((t * 2 + kkw) * 4 + c4w) * 2 + 1) * 16 + l15) * 8 + e0] =
                make_uint2(pack2bf(a11[0], a11[1]), pack2bf(a11[2], a11[3]));
        }
        __syncthreads();                              // B2: hwT complete

        // ---- GEMM2: oacc += M_g @ hw, per slot K=64 (2 kk-steps) ----
#pragma unroll
        for (int t = 0; t < 4; ++t) {
            u32 gt = (u32)gs[t];                      // -1 -> 0xffffffff: never matches
#pragma unroll
            for (int kk = 0; kk < 2; ++kk) {
                u32 wa = gpk[kk * 2], wc = gpk[kk * 2 + 1];
                union { u16 hx[8]; bf16x8 v; } mu;
#pragma unroll
                for (int bb_ = 0; bb_ < 4; ++bb_)
                    mu.hx[bb_]     = (((wa >> (bb_ * 8)) & 0xffu) == gt) ? (u16)0x3F80 : (u16)0;
#pragma unroll
                for (int bb_ = 0; bb_ < 4; ++bb_)
                    mu.hx[4 + bb_] = (((wc >> (bb_ * 8)) & 0xffu) == gt) ? (u16)0x3F80 : (u16)0;
                bf16x8 bb0 = *(const bf16x8*)&hwT[((((t * 2 + kk) * 4 + q) * 2 + 0) * 16 + l15) * 8];
                bf16x8 bb1 = *(const bf16x8*)&hwT[((((t * 2 + kk) * 4 + q) * 2 + 1) * 16 + l15) * 8];
                oacc0 = __builtin_amdgcn_mfma_f32_16x16x32_bf16(mu.v, bb0, oacc0, 0, 0, 0);
                oacc1 = __builtin_amdgcn_mfma_f32_16x16x32_bf16(mu.v, bb1, oacc1, 0, 0, 0);
            }
        }
    }

    // ---- epilogue: i = wv*16 + q*4 + r, c = ch*32 + ni*16 + l15 ----
    size_t ob = ((size_t)scene * PEDS + wv * 16 + q * 4) * POOL + ch * 32 + l15;
#pragma unroll
    for (int r = 0; r < 4; ++r) {
        out[ob + (size_t)r * POOL]      = oacc0[r] + bv0;
        out[ob + (size_t)r * POOL + 16] = oacc1[r] + bv1;
    }
}

extern "C" void kernel_launch(void* const* d_in, const int* in_sizes, int n_in,
                              void* d_out, int out_size, void* d_ws, size_t ws_size,
                              hipStream_t stream) {
    const float* h    = (const float*)d_in[0];
    const float* pos  = (const float*)d_in[1];
    const float* w    = (const float*)d_in[2];
    const float* bias = (const float*)d_in[3];
    float* out = (float*)d_out;

    const int total = in_sizes[0] / HIDDEN;   // 16384
    const int B     = total / PEDS;           // 256

    hipLaunchKernelGGL(social_r6, dim3(B * 2), dim3(256), 0, stream,
                       h, pos, w, bias, out);
}

// Round 7
// 72.676 us; speedup vs baseline: 1.1385x; 1.0005x over previous
//
#include <hip/hip_runtime.h>
#include <cstdint>

#define PEDS   64
#define HIDDEN 128
#define POOL   64
#define GRIDG  4
#define NBHD   2.0f

typedef unsigned short u16;
typedef unsigned int   u32;
typedef __attribute__((ext_vector_type(8))) short bf16x8;
typedef __attribute__((ext_vector_type(4))) float f32x4;

__device__ __forceinline__ u16 f2bf(float f) {
    u32 u = __float_as_uint(f);
    u += 0x7fffu + ((u >> 16) & 1u);   // RNE
    return (u16)(u >> 16);
}
__device__ __forceinline__ u32 pack2bf(float a, float b) {
    return (u32)f2bf(a) | ((u32)f2bf(b) << 16);
}

// Single kernel. Grid = (scene, channel-half), block = 256 (4 waves).
// out = sum_g M_g @ (h @ W_g), both matmuls MFMA.
// Batch 0 stages a SPECULATIVE fixed cell set {5,6,9,10} (the only cells
// reachable for positions spanning < 2*NBHD). Correctness never depends on
// the speculation: GEMM2's M-fragments are built from the true per-lane gidx
// bytes (unused staged cells contribute exactly zero), and any mask bits
// outside the set are handled by the data-driven overflow loop. This makes
// W staging independent of the gidx/shuffle phase -> fully overlapped front
// end, 2 barriers in the common case.
// LDS 48KB: wtab (W bf16 frag-native, 4 cells) 32K | hwT (GEMM2-B frag) 16K.
__global__ __launch_bounds__(256, 2) void social_r7(
    const float* __restrict__ h, const float* __restrict__ pos,
    const float* __restrict__ w, const float* __restrict__ bias,
    float* __restrict__ out)
{
    __shared__ u16 wtab[16384];   // [t][st4][ni][L=q*16+l15][8]  (16B chunks)
    __shared__ u16 hwT[8192];     // [t][kk][jq][ni][l15][8]
    __shared__ u32 wmask[4];

    const int tid  = threadIdx.x;
    const int wv   = tid >> 6;
    const int lane = tid & 63;
    const int l15  = lane & 15;
    const int q    = lane >> 4;
    const int scene = blockIdx.x >> 1;
    const int ch    = blockIdx.x & 1;

    const u32 SPECMASK = (1u << 5) | (1u << 6) | (1u << 9) | (1u << 10);

    // ---- early independent loads ----
    float2 pp = ((const float2*)pos)[(size_t)scene * PEDS + lane];
    const float* hr = h + ((size_t)scene * PEDS + wv * 16 + l15) * HIDDEN + q * 8;
    float4 hf[8];
#pragma unroll
    for (int st4 = 0; st4 < 4; ++st4) {
        hf[st4 * 2]     = *(const float4*)(hr + st4 * 32);
        hf[st4 * 2 + 1] = *(const float4*)(hr + st4 * 32 + 4);
    }
    const float bv0 = bias[ch * 32 + l15];
    const float bv1 = bias[ch * 32 + 16 + l15];

    // ---- speculative W stage for cells {5,6,9,10}: NO dependency on gidx ----
    const int tl    = tid & 127;
    const int c4    = tl & 7;
    const int koct  = tl >> 3;
    const int slot0 = (tid >> 7) * 2;
    {
        const int spec[4] = {5, 6, 9, 10};
#pragma unroll
        for (int tt = 0; tt < 2; ++tt) {
            int t  = slot0 + tt;
            int ge = spec[t];
            const float* src = w + ((size_t)(ge * HIDDEN + koct * 8)) * POOL + ch * 32 + c4 * 4;
            float4 v[8];
#pragma unroll
            for (int e = 0; e < 8; ++e) v[e] = *(const float4*)(src + (size_t)e * POOL);
            const float* vp = (const float*)v;
            int st4 = koct >> 2, ni = c4 >> 2;
            int Lb  = (koct & 3) * 16 + (c4 & 3) * 4;
            uint4* dst = (uint4*)wtab + ((t * 4 + st4) * 2 + ni) * 64 + Lb;
#pragma unroll
            for (int ii = 0; ii < 4; ++ii) {
                dst[ii] = make_uint4(
                    pack2bf(vp[0 * 4 + ii], vp[1 * 4 + ii]),
                    pack2bf(vp[2 * 4 + ii], vp[3 * 4 + ii]),
                    pack2bf(vp[4 * 4 + ii], vp[5 * 4 + ii]),
                    pack2bf(vp[6 * 4 + ii], vp[7 * 4 + ii]));
            }
        }
    }

    // ---- in-register gidx (overlaps the staging stores above) ----
    // i = wv*16 + l15, j = kk*32 + q*8 + e
    const int i = wv * 16 + l15;
    const float pxi = __shfl(pp.x, i), pyi = __shfl(pp.y, i);
    const float scale = (float)GRIDG / (2.0f * NBHD);
    u32 gpk[4] = {0u, 0u, 0u, 0u};
    u32 um = 0u;
#pragma unroll
    for (int kk = 0; kk < 2; ++kk) {
#pragma unroll
        for (int e = 0; e < 8; ++e) {
            int j = kk * 32 + q * 8 + e;
            float rx = __shfl(pp.x, j) - pxi;
            float ry = __shfl(pp.y, j) - pyi;
            u32 gb = 0xffu;
            if ((i != j) && (fabsf(rx) <= NBHD) && (fabsf(ry) <= NBHD)) {
                int gx = (int)floorf((rx + NBHD) * scale); gx = min(max(gx, 0), GRIDG - 1);
                int gy = (int)floorf((ry + NBHD) * scale); gy = min(max(gy, 0), GRIDG - 1);
                gb = (u32)(gy * GRIDG + gx);
                um |= 1u << gb;
            }
            gpk[kk * 2 + (e >> 2)] |= gb << ((e & 3) * 8);
        }
    }
#pragma unroll
    for (int off = 32; off; off >>= 1) um |= __shfl_xor(um, off);
    if (lane == 0) wmask[wv] = um;

    // ---- pack A-frags (pure VALU; overlaps outstanding memory) ----
    bf16x8 af[4];
#pragma unroll
    for (int st4 = 0; st4 < 4; ++st4) {
        union { u32 u[4]; bf16x8 v; } uu;
        uu.u[0] = pack2bf(hf[st4 * 2].x,     hf[st4 * 2].y);
        uu.u[1] = pack2bf(hf[st4 * 2].z,     hf[st4 * 2].w);
        uu.u[2] = pack2bf(hf[st4 * 2 + 1].x, hf[st4 * 2 + 1].y);
        uu.u[3] = pack2bf(hf[st4 * 2 + 1].z, hf[st4 * 2 + 1].w);
        af[st4] = uu.v;
    }

    __syncthreads();                                  // B0: wtab + wmask
    u32 mask = wmask[0] | wmask[1] | wmask[2] | wmask[3];
    mask = __builtin_amdgcn_readfirstlane(mask);

    f32x4 oacc0 = (f32x4){0.f, 0.f, 0.f, 0.f};
    f32x4 oacc1 = (f32x4){0.f, 0.f, 0.f, 0.f};

    const int kkw = wv >> 1;
    const int jqw = (wv & 1) * 2 + (q >> 1);
    const int e0  = (q & 1) * 4;

    // ---- batch 0: GEMM1 over the 4 speculative slots ----
#pragma unroll
    for (int t = 0; t < 4; ++t) {
        f32x4 a10 = (f32x4){0.f, 0.f, 0.f, 0.f};
        f32x4 a11 = (f32x4){0.f, 0.f, 0.f, 0.f};
#pragma unroll
        for (int st4 = 0; st4 < 4; ++st4) {
            bf16x8 b0 = *(const bf16x8*)&wtab[(((t * 4 + st4) * 2 + 0) * 64 + lane) * 8];
            bf16x8 b1 = *(const bf16x8*)&wtab[(((t * 4 + st4) * 2 + 1) * 64 + lane) * 8];
            a10 = __builtin_amdgcn_mfma_f32_16x16x32_bf16(af[st4], b0, a10, 0, 0, 0);
            a11 = __builtin_amdgcn_mfma_f32_16x16x32_bf16(af[st4], b1, a11, 0, 0, 0);
        }
        *(uint2*)&hwT[((((t * 2 + kkw) * 4 + jqw) * 2 + 0) * 16 + l15) * 8 + e0] =
            make_uint2(pack2bf(a10[0], a10[1]), pack2bf(a10[2], a10[3]));
        *(uint2*)&hwT[((((t * 2 + kkw) * 4 + jqw) * 2 + 1) * 16 + l15) * 8 + e0] =
            make_uint2(pack2bf(a11[0], a11[1]), pack2bf(a11[2], a11[3]));
    }
    __syncthreads();                                  // B1: hwT complete

    // ---- batch 0: GEMM2 vs constant cells ----
    {
        const int spec[4] = {5, 6, 9, 10};
#pragma unroll
        for (int t = 0; t < 4; ++t) {
            u32 gt = (u32)spec[t];
#pragma unroll
            for (int kk = 0; kk < 2; ++kk) {
                u32 wa = gpk[kk * 2], wc = gpk[kk * 2 + 1];
                union { u16 hx[8]; bf16x8 v; } mu;
#pragma unroll
                for (int bb_ = 0; bb_ < 4; ++bb_)
                    mu.hx[bb_]     = (((wa >> (bb_ * 8)) & 0xffu) == gt) ? (u16)0x3F80 : (u16)0;
#pragma unroll
                for (int bb_ = 0; bb_ < 4; ++bb_)
                    mu.hx[4 + bb_] = (((wc >> (bb_ * 8)) & 0xffu) == gt) ? (u16)0x3F80 : (u16)0;
                bf16x8 bb0 = *(const bf16x8*)&hwT[((((t * 2 + kk) * 4 + q) * 2 + 0) * 16 + l15) * 8];
                bf16x8 bb1 = *(const bf16x8*)&hwT[((((t * 2 + kk) * 4 + q) * 2 + 1) * 16 + l15) * 8];
                oacc0 = __builtin_amdgcn_mfma_f32_16x16x32_bf16(mu.v, bb0, oacc0, 0, 0, 0);
                oacc1 = __builtin_amdgcn_mfma_f32_16x16x32_bf16(mu.v, bb1, oacc1, 0, 0, 0);
            }
        }
    }

    // ---- overflow loop: cells outside the speculative set (data-driven) ----
    u32 rem = mask & ~SPECMASK;
    while (rem) {
        int gs[4];
#pragma unroll
        for (int t = 0; t < 4; ++t) {
            gs[t] = rem ? (__ffs(rem) - 1) : -1;
            if (rem) rem &= rem - 1u;
        }
        __syncthreads();                              // prior hwT reads done
#pragma unroll
        for (int tt = 0; tt < 2; ++tt) {
            int t  = slot0 + tt;
            int ge = gs[t] < 0 ? 0 : gs[t];
            const float* src = w + ((size_t)(ge * HIDDEN + koct * 8)) * POOL + ch * 32 + c4 * 4;
            float4 v[8];
#pragma unroll
            for (int e = 0; e < 8; ++e) v[e] = *(const float4*)(src + (size_t)e * POOL);
            const float* vp = (const float*)v;
            int st4 = koct >> 2, ni = c4 >> 2;
            int Lb  = (koct & 3) * 16 + (c4 & 3) * 4;
            uint4* dst = (uint4*)wtab + ((t * 4 + st4) * 2 + ni) * 64 + Lb;
#pragma unroll
            for (int ii = 0; ii < 4; ++ii) {
                dst[ii] = make_uint4(
                    pack2bf(vp[0 * 4 + ii], vp[1 * 4 + ii]),
                    pack2bf(vp[2 * 4 + ii], vp[3 * 4 + ii]),
                    pack2bf(vp[4 * 4 + ii], vp[5 * 4 + ii]),
                    pack2bf(vp[6 * 4 + ii], vp[7 * 4 + ii]));
            }
        }
        __syncthreads();                              // wtab staged
#pragma unroll
        for (int t = 0; t < 4; ++t) {
            f32x4 a10 = (f32x4){0.f, 0.f, 0.f, 0.f};
            f32x4 a11 = (f32x4){0.f, 0.f, 0.f, 0.f};
#pragma unroll
            for (int st4 = 0; st4 < 4; ++st4) {
                bf16x8 b0 = *(const bf16x8*)&wtab[(((t * 4 + st4) * 2 + 0) * 64 + lane) * 8];
                bf16x8 b1 = *(const bf16x8*)&wtab[(((t * 4 + st4) * 2 + 1) * 64 + lane) * 8];
                a10 = __builtin_amdgcn_mfma_f32_16x16x32_bf16(af[st4], b0, a10, 0, 0, 0);
                a11 = __builtin_amdgcn_mfma_f32_16x16x32_bf16(af[st4], b1, a11, 0, 0, 0);
            }
            *(uint2*)&hwT[((((t * 2 + kkw) * 4 + jqw) * 2 + 0) * 16 + l15) * 8 + e0] =
                make_uint2(pack2bf(a10[0], a10[1]), pack2bf(a10[2], a10[3]));
            *(uint2*)&hwT[((((t * 2 + kkw) * 4 + jqw) * 2 + 1) * 16 + l15) * 8 + e0] =
                make_uint2(pack2bf(a11[0], a11[1]), pack2bf(a11[2], a11[3]));
        }
        __syncthreads();                              // hwT complete
#pragma unroll
        for (int t = 0; t < 4; ++t) {
            u32 gt = (u32)gs[t];                      // -1 never matches a byte
#pragma unroll
            for (int kk = 0; kk < 2; ++kk) {
                u32 wa = gpk[kk * 2], wc = gpk[kk * 2 + 1];
                union { u16 hx[8]; bf16x8 v; } mu;
#pragma unroll
                for (int bb_ = 0; bb_ < 4; ++bb_)
                    mu.hx[bb_]     = (((wa >> (bb_ * 8)) & 0xffu) == gt) ? (u16)0x3F80 : (u16)0;
#pragma unroll
                for (int bb_ = 0; bb_ < 4; ++bb_)
                    mu.hx[4 + bb_] = (((wc >> (bb_ * 8)) & 0xffu) == gt) ? (u16)0x3F80 : (u16)0;
                bf16x8 bb0 = *(const bf16x8*)&hwT[((((t * 2 + kk) * 4 + q) * 2 + 0) * 16 + l15) * 8];
                bf16x8 bb1 = *(const bf16x8*)&hwT[((((t * 2 + kk) * 4 + q) * 2 + 1) * 16 + l15) * 8];
                oacc0 = __builtin_amdgcn_mfma_f32_16x16x32_bf16(mu.v, bb0, oacc0, 0, 0, 0);
                oacc1 = __builtin_amdgcn_mfma_f32_16x16x32_bf16(mu.v, bb1, oacc1, 0, 0, 0);
            }
        }
    }

    // ---- epilogue: i = wv*16 + q*4 + r, c = ch*32 + ni*16 + l15 ----
    size_t ob = ((size_t)scene * PEDS + wv * 16 + q * 4) * POOL + ch * 32 + l15;
#pragma unroll
    for (int r = 0; r < 4; ++r) {
        out[ob + (size_t)r * POOL]      = oacc0[r] + bv0;
        out[ob + (size_t)r * POOL + 16] = oacc1[r] + bv1;
    }
}

extern "C" void kernel_launch(void* const* d_in, const int* in_sizes, int n_in,
                              void* d_out, int out_size, void* d_ws, size_t ws_size,
                              hipStream_t stream) {
    const float* h    = (const float*)d_in[0];
    const float* pos  = (const float*)d_in[1];
    const float* w    = (const float*)d_in[2];
    const float* bias = (const float*)d_in[3];
    float* out = (float*)d_out;

    const int total = in_sizes[0] / HIDDEN;   // 16384
    const int B     = total / PEDS;           // 256

    hipLaunchKernelGGL(social_r7, dim3(B * 2), dim3(256), 0, stream,
                       h, pos, w, bias, out);
}